// Round 1
// baseline (499.349 us; speedup 1.0000x reference)
//
#include <hip/hip_runtime.h>
#include <math.h>

#define TS   32
#define HALO 10
#define TDIM (TS + HALO)   // 42

// -------------------- fused SSIM-level kernel --------------------
// One block computes a TSxTS tile of the VALID conv output for one (b,c)
// plane: loads 42x42 of img1/img2, horizontal 11-tap pass for the 5
// channels (x1, x2, x1^2, x2^2, x1*x2), vertical pass + SSIM math,
// block-reduce, double atomicAdd into sums[level] / sums[5+level].
__global__ __launch_bounds__(256)
void msssim_level_kernel(const float* __restrict__ img1,
                         const float* __restrict__ img2,
                         int H, int level, double* __restrict__ sums)
{
    __shared__ float sA[TDIM][TDIM];
    __shared__ float sB[TDIM][TDIM];
    __shared__ float h1 [TDIM][TS];
    __shared__ float h2 [TDIM][TS];
    __shared__ float h11[TDIM][TS];
    __shared__ float h22[TDIM][TS];
    __shared__ float h12[TDIM][TS];
    __shared__ float g[11];
    __shared__ float wred[4][2];

    const int tid = threadIdx.x;
    if (tid == 0) {
        // Gaussian window, sigma=1.5, size 11, normalized (double precision)
        double tmp[11], s = 0.0;
        for (int i = 0; i < 11; ++i) {
            double d = (double)(i - 5);
            tmp[i] = exp(-(d * d) / 4.5);
            s += tmp[i];
        }
        for (int i = 0; i < 11; ++i) g[i] = (float)(tmp[i] / s);
    }

    const int Hout = H - HALO;
    const int oy0 = blockIdx.y * TS;
    const int ox0 = blockIdx.x * TS;
    const long long base = (long long)blockIdx.z * H * H;

    // ---- stage 42x42 input tiles (zero-fill OOB; OOB never feeds a valid output)
    for (int w = tid; w < TDIM * TDIM; w += 256) {
        const int r = w / TDIM, c = w % TDIM;
        const int y = oy0 + r, x = ox0 + c;
        float a = 0.f, b = 0.f;
        if (y < H && x < H) {
            const long long idx = base + (long long)y * H + x;
            a = img1[idx];
            b = img2[idx];
        }
        sA[r][c] = a;
        sB[r][c] = b;
    }
    __syncthreads();

    // ---- horizontal 11-tap pass, 5 channels, rows 0..41 x cols 0..31
    for (int w = tid; w < TDIM * TS; w += 256) {
        const int r = w / TS, c = w % TS;
        float a1 = 0.f, a2 = 0.f, a11 = 0.f, a22 = 0.f, a12 = 0.f;
        #pragma unroll
        for (int k = 0; k < 11; ++k) {
            const float wk = g[k];
            const float x1 = sA[r][c + k];
            const float x2 = sB[r][c + k];
            a1  += wk * x1;
            a2  += wk * x2;
            a11 += wk * x1 * x1;
            a22 += wk * x2 * x2;
            a12 += wk * x1 * x2;
        }
        h1 [r][c] = a1;
        h2 [r][c] = a2;
        h11[r][c] = a11;
        h22[r][c] = a22;
        h12[r][c] = a12;
    }
    __syncthreads();

    // ---- vertical pass + SSIM pointwise
    const float C1 = 4.0e-4f;   // (0.01*2)^2
    const float C2 = 3.6e-3f;   // (0.03*2)^2
    float ssim_acc = 0.f, cs_acc = 0.f;
    for (int w = tid; w < TS * TS; w += 256) {
        const int r = w / TS, c = w % TS;
        const int y = oy0 + r, x = ox0 + c;
        if (y < Hout && x < Hout) {
            float mu1 = 0.f, mu2 = 0.f, m11 = 0.f, m22 = 0.f, m12 = 0.f;
            #pragma unroll
            for (int k = 0; k < 11; ++k) {
                const float wk = g[k];
                mu1 += wk * h1 [r + k][c];
                mu2 += wk * h2 [r + k][c];
                m11 += wk * h11[r + k][c];
                m22 += wk * h22[r + k][c];
                m12 += wk * h12[r + k][c];
            }
            const float mu1s = mu1 * mu1;
            const float mu2s = mu2 * mu2;
            const float mu12 = mu1 * mu2;
            const float s1  = m11 - mu1s;
            const float s2  = m22 - mu2s;
            const float s12 = m12 - mu12;
            const float v1 = 2.f * s12 + C2;
            const float v2 = s1 + s2 + C2;
            cs_acc   += v1 / v2;
            ssim_acc += ((2.f * mu12 + C1) * v1) / ((mu1s + mu2s + C1) * v2);
        }
    }

    // ---- block reduction: 64-lane shuffle tree, then across 4 waves
    #pragma unroll
    for (int off = 32; off > 0; off >>= 1) {
        ssim_acc += __shfl_down(ssim_acc, off);
        cs_acc   += __shfl_down(cs_acc, off);
    }
    const int wave = tid >> 6;
    if ((tid & 63) == 0) { wred[wave][0] = ssim_acc; wred[wave][1] = cs_acc; }
    __syncthreads();
    if (tid == 0) {
        const float s = wred[0][0] + wred[1][0] + wred[2][0] + wred[3][0];
        const float c = wred[0][1] + wred[1][1] + wred[2][1] + wred[3][1];
        atomicAdd(&sums[level],     (double)s);
        atomicAdd(&sums[5 + level], (double)c);
    }
}

// -------------------- 2x2 average pool (both images) --------------------
__global__ __launch_bounds__(256)
void msssim_pool_kernel(const float* __restrict__ in1,
                        const float* __restrict__ in2,
                        float* __restrict__ out1,
                        float* __restrict__ out2,
                        int Hin)
{
    const int Hout = Hin >> 1;
    const long long total = 48LL * Hout * Hout;   // B*C = 48
    for (long long i = (long long)blockIdx.x * 256 + threadIdx.x;
         i < total; i += (long long)gridDim.x * 256) {
        const int x = (int)(i % Hout);
        const long long t = i / Hout;
        const int y = (int)(t % Hout);
        const int bc = (int)(t / Hout);
        const long long ib = (long long)bc * Hin * Hin + (long long)(2 * y) * Hin + 2 * x;
        const long long ob = (long long)bc * Hout * Hout + (long long)y * Hout + x;
        out1[ob] = 0.25f * (in1[ib] + in1[ib + 1] + in1[ib + Hin] + in1[ib + Hin + 1]);
        out2[ob] = 0.25f * (in2[ib] + in2[ib + 1] + in2[ib + Hin] + in2[ib + Hin + 1]);
    }
}

// -------------------- final combine --------------------
__global__ void msssim_final_kernel(const double* __restrict__ sums,
                                    float* __restrict__ out)
{
    if (threadIdx.x == 0 && blockIdx.x == 0) {
        const double W[5] = {0.0448, 0.2856, 0.3001, 0.2363, 0.1333};
        const int Houts[5] = {502, 246, 118, 54, 22};
        double mssim[5], mcs[5];
        for (int l = 0; l < 5; ++l) {
            const double cnt = 48.0 * (double)Houts[l] * (double)Houts[l];
            mssim[l] = (sums[l]     / cnt + 1.0) * 0.5;
            mcs[l]   = (sums[5 + l] / cnt + 1.0) * 0.5;
        }
        // prod(pow1[:-1] * pow2[-1]) with pow2[-1] broadcast over 4 elems
        const double p2 = pow(mssim[4], W[4]);
        double prod = 1.0;
        for (int l = 0; l < 4; ++l) prod *= pow(mcs[l], W[l]) * p2;
        out[0] = (float)(1.0 - prod);
    }
}

// -------------------- launch --------------------
extern "C" void kernel_launch(void* const* d_in, const int* in_sizes, int n_in,
                              void* d_out, int out_size, void* d_ws, size_t ws_size,
                              hipStream_t stream)
{
    const float* img1 = (const float*)d_in[0];   // "output"
    const float* img2 = (const float*)d_in[1];   // "gt"
    float* out = (float*)d_out;
    (void)in_sizes; (void)n_in; (void)out_size; (void)ws_size;

    // workspace layout
    char* ws = (char*)d_ws;
    double* sums = (double*)ws;                      // 10 doubles
    float* X1 = (float*)(ws + 256);                  // 3,145,728 floats (level1 / level3)
    float* X2 = X1 + 3145728;
    float* Y1 = X2 + 3145728;                        // 786,432 floats (level2 / level4)
    float* Y2 = Y1 + 786432;

    hipMemsetAsync(sums, 0, 10 * sizeof(double), stream);

    auto launch_level = [&](const float* a, const float* b, int H, int level) {
        const int Hout = H - HALO;
        const int t = (Hout + TS - 1) / TS;
        dim3 grid(t, t, 48);
        hipLaunchKernelGGL(msssim_level_kernel, grid, dim3(256), 0, stream,
                           a, b, H, level, sums);
    };
    auto launch_pool = [&](const float* a, const float* b, float* oa, float* ob, int Hin) {
        const int Hout = Hin >> 1;
        const long long total = 48LL * Hout * Hout;
        int blocks = (int)((total + 255) / 256);
        if (blocks > 8192) blocks = 8192;
        hipLaunchKernelGGL(msssim_pool_kernel, dim3(blocks), dim3(256), 0, stream,
                           a, b, oa, ob, Hin);
    };

    // level 0 (512)
    launch_level(img1, img2, 512, 0);
    launch_pool(img1, img2, X1, X2, 512);
    // level 1 (256)
    launch_level(X1, X2, 256, 1);
    launch_pool(X1, X2, Y1, Y2, 256);
    // level 2 (128)
    launch_level(Y1, Y2, 128, 2);
    launch_pool(Y1, Y2, X1, X2, 128);
    // level 3 (64)
    launch_level(X1, X2, 64, 3);
    launch_pool(X1, X2, Y1, Y2, 64);
    // level 4 (32)
    launch_level(Y1, Y2, 32, 4);

    hipLaunchKernelGGL(msssim_final_kernel, dim3(1), dim3(64), 0, stream, sums, out);
}